// Round 2
// baseline (795.389 us; speedup 1.0000x reference)
//
#include <hip/hip_runtime.h>
#include <hip/hip_fp16.h>

// MoE gate: logits = x @ W^T (M=32768, N=64, K=4096 fp32), softmax over 64,
// top-8 (vals fp32, idx as float). Split-f16 MFMA GEMM:
//   x = xh + xl, 64*W = wh + wl  (f16 each); logit = (xh*wh + xl*wh + xh*wl)/64
// Logit noise vs fp32 ref ~2e-6 (MFMA accumulation order). Near-tie ranks in
// the top-9 (rel gap < 5e-5) are flagged and re-resolved exactly in fp64 by a
// second tiny kernel (~0.6% of tokens) -> index ordering matches the fp64/np
// reference exactly.
//
// Block: 64 tokens x 64 experts, 256 thr (4 waves = 4 M-tiles of 16), BK=64.
// 512 blocks -> 2 blocks/CU. LDS tiles stored as fragment-contiguous 1KB
// blobs => all ds_read_b128 conflict-free. Verified 16x16x32 layouts:
// A/B^T lane->[l&15][(l>>4)*8+j]; C/D col=l&15, row=(l>>4)*4+reg.

typedef _Float16 half8 __attribute__((ext_vector_type(8)));
typedef float floatx4 __attribute__((ext_vector_type(4)));

constexpr int D = 4096;      // d_hidden
constexpr int NE = 64;       // experts
constexpr int MBLK = 64;     // tokens per block
constexpr int BK = 64;       // k per chunk
constexpr int KCHUNKS = D / BK;

__device__ __forceinline__ void split8(float4 p, float4 q, float sc, half8& h, half8& l) {
    float f[8] = {p.x, p.y, p.z, p.w, q.x, q.y, q.z, q.w};
#pragma unroll
    for (int i = 0; i < 8; ++i) {
        float v = f[i] * sc;
        _Float16 hi = (_Float16)v;
        h[i] = hi;
        l[i] = (_Float16)(v - (float)hi);
    }
}

__global__ __launch_bounds__(256, 2) void moe_gate_kernel(
    const float* __restrict__ x, const float* __restrict__ wg,
    float* __restrict__ out_vals, float* __restrict__ out_idx,
    int* __restrict__ flag_ws, int cap)
{
    __shared__ alignas(16) _Float16 Xh[MBLK * BK];   // 8 KB each
    __shared__ alignas(16) _Float16 Xl[MBLK * BK];
    __shared__ alignas(16) _Float16 Wh[NE * BK];
    __shared__ alignas(16) _Float16 Wl[NE * BK];

    const int tid  = (int)threadIdx.x;
    const int lane = tid & 63;
    const int wv   = tid >> 6;             // wave id == M-tile id
    const int tb   = (int)blockIdx.x * MBLK;

    // Staging slots: 512 (row,k8) slots per operand, 2 per thread.
    const int s0 = tid, s1 = tid + 256;
    const int t0 = s0 >> 3, k80 = s0 & 7;  // rows 0..31
    const int t1 = s1 >> 3, k81 = s1 & 7;  // rows 32..63

    const float* xp0 = x  + (size_t)(tb + t0) * D + k80 * 8;
    const float* xp1 = x  + (size_t)(tb + t1) * D + k81 * 8;
    const float* wp0 = wg + (size_t)t0 * D + k80 * 8;
    const float* wp1 = wg + (size_t)t1 * D + k81 * 8;

    // blob offset (halfs): ((tile*2 + kstep)*64 + quad*16 + row16) * 8
    const int xo0 = (((t0 >> 4) * 2 + (k80 >> 2)) * 64 + (k80 & 3) * 16 + (t0 & 15)) * 8;
    const int xo1 = (((t1 >> 4) * 2 + (k81 >> 2)) * 64 + (k81 & 3) * 16 + (t1 & 15)) * 8;

    float4 ra0, ra1, rb0, rb1, rc0, rc1, rd0, rd1;
#define LOADCHUNK(kc) do { const int off_ = (kc) * BK;                        \
        ra0 = *(const float4*)(xp0 + off_); ra1 = *(const float4*)(xp0 + off_ + 4); \
        rb0 = *(const float4*)(xp1 + off_); rb1 = *(const float4*)(xp1 + off_ + 4); \
        rc0 = *(const float4*)(wp0 + off_); rc1 = *(const float4*)(wp0 + off_ + 4); \
        rd0 = *(const float4*)(wp1 + off_); rd1 = *(const float4*)(wp1 + off_ + 4); } while (0)

    floatx4 acc[4] = {{0,0,0,0},{0,0,0,0},{0,0,0,0},{0,0,0,0}};

    LOADCHUNK(0);
    for (int kc = 0; kc < KCHUNKS; ++kc) {
        half8 hx0, lx0, hx1, lx1, hw0, lw0, hw1, lw1;
        split8(ra0, ra1, 1.0f,  hx0, lx0);
        split8(rb0, rb1, 1.0f,  hx1, lx1);
        split8(rc0, rc1, 64.0f, hw0, lw0);   // scale W by 64: keeps wl normal-range f16
        split8(rd0, rd1, 64.0f, hw1, lw1);
        if (kc) __syncthreads();             // prior chunk's frags fully consumed
        *(half8*)(Xh + xo0) = hx0; *(half8*)(Xl + xo0) = lx0;
        *(half8*)(Xh + xo1) = hx1; *(half8*)(Xl + xo1) = lx1;
        *(half8*)(Wh + xo0) = hw0; *(half8*)(Wl + xo0) = lw0;
        *(half8*)(Wh + xo1) = hw1; *(half8*)(Wl + xo1) = lw1;
        if (kc + 1 < KCHUNKS) LOADCHUNK(kc + 1);  // in flight during MFMA phase
        __syncthreads();
#pragma unroll
        for (int ks = 0; ks < 2; ++ks) {
            const half8 ah = *(const half8*)(Xh + ((wv * 2 + ks) * 64 + lane) * 8);
            const half8 al = *(const half8*)(Xl + ((wv * 2 + ks) * 64 + lane) * 8);
#pragma unroll
            for (int nt = 0; nt < 4; ++nt) {
                const half8 bh = *(const half8*)(Wh + ((nt * 2 + ks) * 64 + lane) * 8);
                const half8 bl = *(const half8*)(Wl + ((nt * 2 + ks) * 64 + lane) * 8);
                acc[nt] = __builtin_amdgcn_mfma_f32_16x16x32_f16(ah, bh, acc[nt], 0, 0, 0);
                acc[nt] = __builtin_amdgcn_mfma_f32_16x16x32_f16(al, bh, acc[nt], 0, 0, 0);
                acc[nt] = __builtin_amdgcn_mfma_f32_16x16x32_f16(ah, bl, acc[nt], 0, 0, 0);
            }
        }
    }
#undef LOADCHUNK

    // Epilogue: lane holds experts {nt*16 + (lane&15)} for tokens
    // tb + wv*16 + (lane>>4)*4 + r. Softmax + top-9 via 16-lane xor-shuffles;
    // adjacent near-ties (rel gap < 5e-5) flag the token for fp64 refinement.
    const int g = lane >> 4, c = lane & 15;
    const float inv64 = 0.015625f;           // undo W*64 scale (exact pow2)
#pragma unroll
    for (int r = 0; r < 4; ++r) {
        float s[4];
#pragma unroll
        for (int nt = 0; nt < 4; ++nt) s[nt] = acc[nt][r] * inv64;
        float m = fmaxf(fmaxf(s[0], s[1]), fmaxf(s[2], s[3]));
#pragma unroll
        for (int off = 1; off < 16; off <<= 1) m = fmaxf(m, __shfl_xor(m, off));
        float p[4]; float t = 0.0f;
#pragma unroll
        for (int nt = 0; nt < 4; ++nt) { p[nt] = expf(s[nt] - m); t += p[nt]; }
#pragma unroll
        for (int off = 1; off < 16; off <<= 1) t += __shfl_xor(t, off);
        const float inv = 1.0f / t;
#pragma unroll
        for (int nt = 0; nt < 4; ++nt) p[nt] *= inv;

        const int tok = tb + wv * 16 + g * 4 + r;
        float prev = 0.0f;
        bool flagged = false;
#pragma unroll
        for (int i = 0; i < 9; ++i) {
            float bv = p[0]; int bn = 0;
            if (p[1] > bv) { bv = p[1]; bn = 1; }   // strict > : ties -> lower expert
            if (p[2] > bv) { bv = p[2]; bn = 2; }
            if (p[3] > bv) { bv = p[3]; bn = 3; }
            int be = bn * 16 + c;
#pragma unroll
            for (int off = 1; off < 16; off <<= 1) {
                float ov = __shfl_xor(bv, off);
                int   oe = __shfl_xor(be, off);
                if (ov > bv || (ov == bv && oe < be)) { bv = ov; be = oe; }
            }
            if (i > 0 && (prev - bv) < prev * 5e-5f) flagged = true;
            prev = bv;
            if (i < 8 && c == i) {
                out_vals[(size_t)tok * 8 + i] = bv;
                out_idx [(size_t)tok * 8 + i] = (float)be;
            }
            if (c == (be & 15)) p[be >> 4] = -1.0f; // remove winner (scores >= 0)
        }
        if (flagged && c == 0 && cap > 0) {
            int pos = atomicAdd(flag_ws, 1);
            if (pos < cap) flag_ws[4 + pos] = tok;
        }
    }
}

// fp64 exact re-resolution for flagged tokens (near-tied top-9 ranks).
// 256 thr = 64 experts x 4 k-chunks; fp64 dot, LDS reduce, wave-0 fp64
// softmax + top-8 (lower-index tie-break, matches lax.top_k / np).
__global__ __launch_bounds__(256) void moe_refine_kernel(
    const float* __restrict__ x, const float* __restrict__ wg,
    float* __restrict__ out_vals, float* __restrict__ out_idx,
    const int* __restrict__ flag_ws, int cap)
{
    const int count = min(flag_ws[0], cap);
    const int* list = flag_ws + 4;
    __shared__ double part[256];
    for (int it = (int)blockIdx.x; it < count; it += (int)gridDim.x) {
        const int tok = list[it];
        const int e = (int)threadIdx.x & 63, ch = (int)threadIdx.x >> 6;
        const float4* xr = (const float4*)(x + (size_t)tok * D + ch * 1024);
        const float4* wr = (const float4*)(wg + (size_t)e * D + ch * 1024);
        double s0 = 0, s1 = 0, s2 = 0, s3 = 0;
#pragma unroll 4
        for (int k = 0; k < 256; ++k) {
            float4 a = xr[k], b = wr[k];
            s0 += (double)a.x * (double)b.x; s1 += (double)a.y * (double)b.y;
            s2 += (double)a.z * (double)b.z; s3 += (double)a.w * (double)b.w;
        }
        part[threadIdx.x] = (s0 + s1) + (s2 + s3);
        __syncthreads();
        if (threadIdx.x < 64) {
            double l = part[e] + part[e + 64] + part[e + 128] + part[e + 192];
            double m = l;
#pragma unroll
            for (int off = 1; off < 64; off <<= 1) m = fmax(m, __shfl_xor(m, off));
            double p = exp(l - m), Z = p;
#pragma unroll
            for (int off = 1; off < 64; off <<= 1) Z += __shfl_xor(Z, off);
            double key = l;
            for (int i = 0; i < 8; ++i) {
                double bk = key; int bi = e; double bp = p;
#pragma unroll
                for (int off = 1; off < 64; off <<= 1) {
                    double ok = __shfl_xor(bk, off);
                    int    oi = __shfl_xor(bi, off);
                    double op = __shfl_xor(bp, off);
                    if (ok > bk || (ok == bk && oi < bi)) { bk = ok; bi = oi; bp = op; }
                }
                if (e == i) {
                    out_vals[(size_t)tok * 8 + i] = (float)(bp / Z);
                    out_idx [(size_t)tok * 8 + i] = (float)bi;
                }
                if (e == bi) key = -1.0e300;
            }
        }
        __syncthreads();
    }
}

extern "C" void kernel_launch(void* const* d_in, const int* in_sizes, int n_in,
                              void* d_out, int out_size, void* d_ws, size_t ws_size,
                              hipStream_t stream) {
    const float* x  = (const float*)d_in[0];
    const float* wg = (const float*)d_in[1];
    const int n_tokens = in_sizes[0] / D;           // 32768
    float* out_vals = (float*)d_out;
    float* out_idx  = out_vals + (size_t)n_tokens * 8;
    int cap = 0;
    if (ws_size > 32) {
        size_t c = (ws_size - 32) / sizeof(int);
        cap = (int)(c > 32768 ? 32768 : c);
    }
    hipMemsetAsync(d_ws, 0, 16, stream);            // zero flag counter (ws re-poisoned 0xAA)
    const int grid = n_tokens / MBLK;               // 512 blocks
    hipLaunchKernelGGL(moe_gate_kernel, dim3(grid), dim3(256), 0, stream,
                       x, wg, out_vals, out_idx, (int*)d_ws, cap);
    hipLaunchKernelGGL(moe_refine_kernel, dim3(256), dim3(256), 0, stream,
                       x, wg, out_vals, out_idx, (const int*)d_ws, cap);
}